// Round 1
// baseline (717.516 us; speedup 1.0000x reference)
//
#include <hip/hip_runtime.h>
#include <hip/hip_bf16.h>

#define BB 8
#define TT 4096
#define CC 1024
#define SS 512

typedef __bf16 bf16x8 __attribute__((ext_vector_type(8)));
typedef float f32x4 __attribute__((ext_vector_type(4)));
typedef unsigned short u16x8 __attribute__((ext_vector_type(8)));

__device__ __forceinline__ float bf2f(unsigned short u) {
  union { unsigned int i; float f; } x; x.i = ((unsigned int)u) << 16; return x.f;
}
__device__ __forceinline__ unsigned short f2bf(float f) {
  __hip_bfloat16 h = __float2bfloat16(f);
  unsigned short u; __builtin_memcpy(&u, &h, 2); return u;
}

// ---------------------------------------------------------------------------
// fp32 -> bf16 convert (+ optional transposed copy). grid (R/64, Cd/64, B),
// block (64,4). in [R][Cd] fp32 -> out_rm [R][Cd] bf16, out_t [Cd][R] bf16.
// ---------------------------------------------------------------------------
__global__ void cvt_transpose(const float* __restrict__ in,
                              unsigned short* __restrict__ out_rm,
                              unsigned short* __restrict__ out_t,
                              int R, int Cd) {
  __shared__ float tile[64][65];
  const long bo = (long)blockIdx.z * R * Cd;
  const int r0 = blockIdx.x * 64, c0 = blockIdx.y * 64;
  const int tx = threadIdx.x, ty = threadIdx.y;
#pragma unroll
  for (int i = 0; i < 16; ++i) {
    int r = ty + i * 4;
    float v = in[bo + (long)(r0 + r) * Cd + c0 + tx];
    tile[r][tx] = v;
    out_rm[bo + (long)(r0 + r) * Cd + c0 + tx] = f2bf(v);
  }
  if (out_t != nullptr) {
    __syncthreads();
#pragma unroll
    for (int i = 0; i < 16; ++i) {
      int c = ty + i * 4;
      out_t[bo + (long)(c0 + c) * R + r0 + tx] = f2bf(tile[tx][c]);
    }
  }
}

// ---------------------------------------------------------------------------
// bf16 tile transpose: in [Rin][Cin] -> out [Cin][Rin]. grid (Rin/64, Cin/64, B),
// block 256 flat. 16B vector loads/stores both sides via LDS tile.
// ---------------------------------------------------------------------------
__global__ void transpose_bf16(const unsigned short* __restrict__ in,
                               unsigned short* __restrict__ out,
                               int Rin, int Cin) {
  __shared__ unsigned short tile[64][72];  // stride 72: keeps 16B alignment
  const long bo = (long)blockIdx.z * Rin * Cin;
  const int r0 = blockIdx.x * 64, c0 = blockIdx.y * 64;
  const int tid = threadIdx.x;
  const int lr = tid >> 3;
  const int lc = (tid & 7) * 8;
#pragma unroll
  for (int p = 0; p < 2; ++p) {
    int r = lr + p * 32;
    *(u16x8*)&tile[r][lc] = *(const u16x8*)&in[bo + (long)(r0 + r) * Cin + c0 + lc];
  }
  __syncthreads();
#pragma unroll
  for (int p = 0; p < 2; ++p) {
    int s = lr + p * 32;
    u16x8 val;
#pragma unroll
    for (int j = 0; j < 8; ++j) val[j] = tile[lc + j][s];
    *(u16x8*)&out[bo + (long)(c0 + s) * Rin + r0 + lc] = val;
  }
}

// ---------------------------------------------------------------------------
// In-place row softmax over bf16 rows of length ROWLEN. One wave per row,
// 4 rows per 256-thread block. grid = total_rows/4.
// ---------------------------------------------------------------------------
template <int ROWLEN>
__global__ __launch_bounds__(256) void row_softmax(unsigned short* __restrict__ sc) {
  constexpr int NV = ROWLEN / 512;  // 16B vectors per lane
  const int lane = threadIdx.x & 63;
  const long row = (long)blockIdx.x * 4 + (threadIdx.x >> 6);
  unsigned short* base = sc + row * (long)ROWLEN;
  u16x8 d[NV];
  float m = -1e30f;
#pragma unroll
  for (int v = 0; v < NV; ++v) {
    d[v] = *(const u16x8*)&base[(v * 64 + lane) * 8];
#pragma unroll
    for (int j = 0; j < 8; ++j) m = fmaxf(m, bf2f(d[v][j]));
  }
#pragma unroll
  for (int off = 32; off >= 1; off >>= 1) m = fmaxf(m, __shfl_xor(m, off, 64));
  float l = 0.f;
#pragma unroll
  for (int v = 0; v < NV; ++v) {
#pragma unroll
    for (int j = 0; j < 8; ++j) {
      float e = __expf(bf2f(d[v][j]) - m);
      l += e;
      d[v][j] = f2bf(e);
    }
  }
#pragma unroll
  for (int off = 32; off >= 1; off >>= 1) l += __shfl_xor(l, off, 64);
  const float inv = 1.f / l;
#pragma unroll
  for (int v = 0; v < NV; ++v) {
    u16x8 o;
#pragma unroll
    for (int j = 0; j < 8; ++j) o[j] = f2bf(bf2f(d[v][j]) * inv);
    *(u16x8*)&base[(v * 64 + lane) * 8] = o;
  }
}

// ---------------------------------------------------------------------------
// GEMM: out[M,N] = alpha * A[M,K] @ Bt[N,K]^T (+ resid). bf16 in, fp32 acc.
// m97 structure: 128x128 tile, BK=64, 4 waves in 2x2, each 4x4 of 16x16x32
// MFMA; global->LDS via width-16 global_load_lds (wave-uniform base+lane*16).
// grid (N/128, M/128, B), block 256. M,N mult of 128; K mult of 64.
// ---------------------------------------------------------------------------
template <bool OUT_BF16, bool RESID>
__global__ __launch_bounds__(256) void gemm_bt(
    const unsigned short* __restrict__ A, int lda, long sA,
    const unsigned short* __restrict__ Bt, int ldb, long sB,
    void* __restrict__ Cout, int ldc, long sC,
    const float* __restrict__ resid, long sR,
    float alpha, int M, int N, int K) {
  __shared__ unsigned short As[128 * 64];
  __shared__ unsigned short Bs[128 * 64];
  const int zb = blockIdx.z;
  const unsigned short* Ab = A + (long)zb * sA;
  const unsigned short* Bb = Bt + (long)zb * sB;
  const int m0 = blockIdx.y * 128;
  const int n0 = blockIdx.x * 128;
  const int tid = threadIdx.x;
  const int lane = tid & 63;
  const int wm = (tid >> 6) & 1;
  const int wn = tid >> 7;
  const int srow = tid >> 3;        // 0..31 staging row
  const int scol = (tid & 7) * 8;   // staging col (elements)
  f32x4 zero = {0.f, 0.f, 0.f, 0.f};
  f32x4 acc[4][4];
#pragma unroll
  for (int i = 0; i < 4; ++i)
#pragma unroll
    for (int j = 0; j < 4; ++j) acc[i][j] = zero;

  for (int k0 = 0; k0 < K; k0 += 64) {
#pragma unroll
    for (int p = 0; p < 4; ++p) {
      int r = srow + p * 32;
      const unsigned short* g = Ab + (long)(m0 + r) * lda + k0 + scol;
      __builtin_amdgcn_global_load_lds(
          (const __attribute__((address_space(1))) void*)g,
          (__attribute__((address_space(3))) void*)&As[r * 64 + scol], 16, 0, 0);
    }
#pragma unroll
    for (int p = 0; p < 4; ++p) {
      int r = srow + p * 32;
      const unsigned short* g = Bb + (long)(n0 + r) * ldb + k0 + scol;
      __builtin_amdgcn_global_load_lds(
          (const __attribute__((address_space(1))) void*)g,
          (__attribute__((address_space(3))) void*)&Bs[r * 64 + scol], 16, 0, 0);
    }
    __syncthreads();
#pragma unroll
    for (int kk = 0; kk < 2; ++kk) {
      const int kof = kk * 32 + (lane >> 4) * 8;
      bf16x8 af[4], bfr[4];
#pragma unroll
      for (int i = 0; i < 4; ++i)
        af[i] = *(const bf16x8*)&As[(wm * 64 + i * 16 + (lane & 15)) * 64 + kof];
#pragma unroll
      for (int j = 0; j < 4; ++j)
        bfr[j] = *(const bf16x8*)&Bs[(wn * 64 + j * 16 + (lane & 15)) * 64 + kof];
#pragma unroll
      for (int i = 0; i < 4; ++i)
#pragma unroll
        for (int j = 0; j < 4; ++j)
          acc[i][j] = __builtin_amdgcn_mfma_f32_16x16x32_bf16(af[i], bfr[j], acc[i][j], 0, 0, 0);
    }
    __syncthreads();
  }
  // epilogue: C/D layout col=lane&15, row=(lane>>4)*4+reg  [m89-verified]
  const int rbase = (lane >> 4) * 4;
  const int cl = lane & 15;
#pragma unroll
  for (int i = 0; i < 4; ++i)
#pragma unroll
    for (int j = 0; j < 4; ++j)
#pragma unroll
      for (int r = 0; r < 4; ++r) {
        int row = m0 + wm * 64 + i * 16 + rbase + r;
        int col = n0 + wn * 64 + j * 16 + cl;
        long idx = (long)row * ldc + col;
        float v = acc[i][j][r] * alpha;
        if (RESID) v += resid[(long)zb * sR + idx];
        if (OUT_BF16)
          ((unsigned short*)Cout)[(long)zb * sC + idx] = f2bf(v);
        else
          ((float*)Cout)[(long)zb * sC + idx] = v;
      }
}

// ---------------------------------------------------------------------------
extern "C" void kernel_launch(void* const* d_in, const int* in_sizes, int n_in,
                              void* d_out, int out_size, void* d_ws, size_t ws_size,
                              hipStream_t stream) {
  const float* x = (const float*)d_in[0];
  const float* kin = (const float*)d_in[1];
  const float* vin = (const float*)d_in[2];

  float* att = (float*)d_out;                    // [B,T,C]
  float* kt = att + (long)BB * TT * CC;          // [B,S,C]
  float* vt = kt + (long)BB * SS * CC;           // [B,S,C]

  // Scratch: att output region (134 MB) exactly holds xb (67 MB) + xT (67 MB);
  // att is written by the LAST gemm, after all consumers of xb/xT are done.
  unsigned short* xb = (unsigned short*)d_out;         // bf16 [B,T,C]
  unsigned short* xT = xb + (long)BB * TT * CC;        // bf16 [B,C,T]

  char* w = (char*)d_ws;
  unsigned short* kb = (unsigned short*)w; w += (long)BB * SS * CC * 2;  // [B,S,C]
  unsigned short* vb = (unsigned short*)w; w += (long)BB * SS * CC * 2;  // [B,S,C]
  unsigned short* vT = (unsigned short*)w; w += (long)BB * CC * SS * 2;  // [B,C,S]
  unsigned short* sc = (unsigned short*)w; w += (long)BB * TT * SS * 2;  // [B,T,S]
  unsigned short* pk = (unsigned short*)w; w += (long)BB * SS * TT * 2;  // [B,S,T]
  // total ws: ~92.3 MB

  const float scale = 0.03125f;  // 1/sqrt(1024)
  dim3 cblk(64, 4);

  // 1-3: convert to bf16 (+ transposes)
  cvt_transpose<<<dim3(TT / 64, CC / 64, BB), cblk, 0, stream>>>(x, xb, xT, TT, CC);
  cvt_transpose<<<dim3(SS / 64, CC / 64, BB), cblk, 0, stream>>>(kin, kb, (unsigned short*)nullptr, SS, CC);
  cvt_transpose<<<dim3(SS / 64, CC / 64, BB), cblk, 0, stream>>>(vin, vb, vT, SS, CC);

  // 4: sc[T,S] = scale * x @ k^T
  gemm_bt<true, false><<<dim3(SS / 128, TT / 128, BB), 256, 0, stream>>>(
      xb, CC, (long)TT * CC, kb, CC, (long)SS * CC, sc, SS, (long)TT * SS,
      nullptr, 0, scale, TT, SS, CC);

  // 5: pk[S,T] = sc^T (raw scores, = k_scores); 6: softmax rows over T
  transpose_bf16<<<dim3(TT / 64, SS / 64, BB), 256, 0, stream>>>(sc, pk, TT, SS);
  row_softmax<TT><<<BB * SS / 4, 256, 0, stream>>>(pk);

  // 7: k_t = P_k @ x + k_t_1   (A=pk[S,T], Bt=xT[C,T])
  gemm_bt<false, true><<<dim3(CC / 128, SS / 128, BB), 256, 0, stream>>>(
      pk, TT, (long)SS * TT, xT, TT, (long)CC * TT, kt, CC, (long)SS * CC,
      kin, (long)SS * CC, 1.f, SS, CC, TT);

  // 8: att P: softmax rows of sc over S (after transpose consumed raw sc)
  row_softmax<SS><<<BB * TT / 4, 256, 0, stream>>>(sc);

  // 9: vsc[S,T] = scale * v @ x^T   (reuse pk buffer)
  gemm_bt<true, false><<<dim3(TT / 128, SS / 128, BB), 256, 0, stream>>>(
      vb, CC, (long)SS * CC, xb, CC, (long)TT * CC, pk, TT, (long)SS * TT,
      nullptr, 0, scale, SS, TT, CC);
  row_softmax<TT><<<BB * SS / 4, 256, 0, stream>>>(pk);

  // 10: v_t = P_v @ x + v_t_1
  gemm_bt<false, true><<<dim3(CC / 128, SS / 128, BB), 256, 0, stream>>>(
      pk, TT, (long)SS * TT, xT, TT, (long)CC * TT, vt, CC, (long)SS * CC,
      vin, (long)SS * CC, 1.f, SS, CC, TT);

  // 11: att = P_att @ v  (A=sc[T,S], Bt=vT[C,S]) — overwrites xb/xT scratch
  gemm_bt<false, false><<<dim3(CC / 128, TT / 128, BB), 256, 0, stream>>>(
      sc, SS, (long)TT * SS, vT, SS, (long)CC * SS, att, CC, (long)TT * CC,
      nullptr, 0, 1.f, TT, CC, SS);
}